// Round 5
// baseline (270.299 us; speedup 1.0000x reference)
//
#include <hip/hip_runtime.h>

// Problem constants
static constexpr int BATCH = 16384;   // rows of x
static constexpr int DIM   = 1024;    // feature dim
static constexpr int NN    = 1024;    // 32*32 grid nodes

typedef _Float16 half8  __attribute__((ext_vector_type(8)));
typedef _Float16 half4v __attribute__((ext_vector_type(4)));
typedef float    f32x4  __attribute__((ext_vector_type(4)));

static constexpr float L2E = 1.44269504088896340736f;

// ---------------------------------------------------------------------------
// prep 1: pack W into MFMA-fragment-major fp16 layout for both GEMMs.
// Fragment (16x16x32 f16 B-operand): lane l supplies
//   B[t_n*16 + (l&15)][t_k*32 + (l>>4)*8 + j], j=0..7  (one half8).
// P1[f=(t_n*32+t_k)][l][8] : B = w[n][d]    (GEMM1: S = x @ w^T)
// P2[f=(t_d*32+t_n)][l][8] : B = w[n][d]^T  (GEMM2: recon = c @ w)
// ---------------------------------------------------------------------------
__global__ __launch_bounds__(256) void prep_pack_kernel(const float* __restrict__ W,
                                                        _Float16* __restrict__ P1,
                                                        _Float16* __restrict__ P2) {
    const int l = threadIdx.x & 63;
    const int v = threadIdx.x >> 6;
    const int f = blockIdx.x * 4 + v;          // 0..2047
    const int hi = f >> 5, lo = f & 31;
    {   // P1: n-tile = hi, k(d)-tile = lo
        int n  = hi * 16 + (l & 15);
        int k0 = lo * 32 + (l >> 4) * 8;
        const float* src = W + (size_t)n * DIM + k0;
        f32x4 a = *(const f32x4*)src;
        f32x4 b = *(const f32x4*)(src + 4);
        half8 h;
#pragma unroll
        for (int q = 0; q < 4; ++q) { h[q] = (_Float16)a[q]; h[4 + q] = (_Float16)b[q]; }
        *(half8*)(P1 + ((size_t)f * 64 + l) * 8) = h;
    }
    {   // P2: d-tile = hi, k(n)-tile = lo
        int d  = hi * 16 + (l & 15);
        int n0 = lo * 32 + (l >> 4) * 8;
        half8 h;
#pragma unroll
        for (int j = 0; j < 8; ++j) h[j] = (_Float16)W[(size_t)(n0 + j) * DIM + d];
        *(half8*)(P2 + ((size_t)f * 64 + l) * 8) = h;
    }
}

// ---------------------------------------------------------------------------
// prep 2: wsqs[n] = L2E * ||w_n||^2   (pre-scaled for exp2 argument folding)
// ---------------------------------------------------------------------------
__global__ __launch_bounds__(256) void wsq_kernel(const float* __restrict__ W,
                                                  float* __restrict__ wsq) {
    const int n = blockIdx.x;
    const int t = threadIdx.x;
    float4 v = *(const float4*)(W + (size_t)n * DIM + 4 * t);
    float ss = v.x * v.x + v.y * v.y + v.z * v.z + v.w * v.w;
#pragma unroll
    for (int o = 32; o > 0; o >>= 1) ss += __shfl_xor(ss, o, 64);
    __shared__ float red[4];
    if ((t & 63) == 0) red[t >> 6] = ss;
    __syncthreads();
    if (t == 0) wsq[n] = L2E * (red[0] + red[1] + red[2] + red[3]);
}

// ---------------------------------------------------------------------------
// FUSED: per block = 64 rows of x.  16 waves x 1024 threads, 256 blocks.
// Wave w owns cols w*64 + ni*16 + (l&15), ni=0..3.
//   Phase A: raw dot acc = x@w^T in regs; x fp32 loaded to regs (nt), cvt
//            fp16, ds_write into xs dbuf.  P1 fragments software-pipelined
//            ACROSS the per-step barrier (in-place reg reuse; T4-style).
//   Phase B (NO-MAX softmax; logits v = 2*acc - wsq lie in ~[-21,18]):
//            e1 = exp2(2*L2E*acc - wsqs[col]); S2 wave-local (shfl), S1
//            cross-wave via one swizzled-LDS round; cu = e1^2*rcp(S1)*rcp(S2)
//            -> cs fp16 (row-unnormalized).
//   Phase C: recon = cu @ w, barrier-free K-loop; bf reg-double-buffered
//            2-deep; row-normalize at epilogue with direct plain stores.
// Element map: row = mi*16+(l>>4)*4+q; col n = w*64+ni*16+(l&15);
//   g1 = n>>5 = w*2+(ni>>1) [p];  g2 = n&31 = (ni&1)*16+(l&15) [j].
// LDS: xs 16K + BIG 128K (red/cs union) + a1 8K + rowred 4K + rowinv.
// ---------------------------------------------------------------------------
__global__ __launch_bounds__(1024, 4) void fused_som_kernel(
    const float* __restrict__ X, const _Float16* __restrict__ P1,
    const _Float16* __restrict__ P2, const float* __restrict__ wsq,
    float* __restrict__ Out) {

    __shared__ __align__(16) _Float16 xs[2][64 * 64];   // 16 KB dbuf
    __shared__ __align__(16) char     BIG[131072];      // red / cs union
    __shared__ __align__(16) float    a1_lds[64 * 32];  // 8 KB (stores 1/S1)
    __shared__ __align__(16) float    rowred[16 * 64];  // 4 KB
    __shared__ __align__(16) float    rowinv[64];

    const int t  = threadIdx.x;
    const int l  = t & 63;
    const int w  = t >> 6;
    const int r0 = blockIdx.x * 64;

    // swizzled index helpers (2-way max bank aliasing for cross-wave reduce)
    auto RIDX = [](int wv, int row, int g2) {
        return (wv * 64 + row) * 32 + (g2 ^ ((row & 4) << 2));
    };
    auto AIDX = [](int row, int g2) {
        return row * 32 + (g2 ^ ((row & 4) << 2));
    };

    // ---------------- Phase A ----------------
    const int srow = t >> 4;                  // staging row 0..63
    const int skq  = t & 15;                  // f32x4 index within 64-k tile

    auto xload = [&](int kt) -> f32x4 {
        return __builtin_nontemporal_load(
            (const f32x4*)(X + (size_t)(r0 + srow) * DIM + kt + skq * 4));
    };
    auto xwrite = [&](int buf, f32x4 v) {
        half4v h;
        h[0] = (_Float16)v[0]; h[1] = (_Float16)v[1];
        h[2] = (_Float16)v[2]; h[3] = (_Float16)v[3];
        int c = skq >> 1;                     // 16-B chunk 0..7
        *(half4v*)&xs[buf][srow * 64 + ((c ^ (srow & 7)) << 3) + ((skq & 1) << 2)] = h;
    };
    // P1 fragment loads for one 32-k subtile (pure global; no LDS dep)
    auto loadB1 = [&](int tk, half8* dst) {
#pragma unroll
        for (int ni = 0; ni < 4; ++ni)
            dst[ni] = *(const half8*)(P1 +
                (((size_t)(w * 4 + ni) * 32 + tk) * 64 + l) * 8);
    };

    f32x4 acc[4][4] = {};
    {   // prologue: tile 0 -> xs[0]
        f32x4 xv = xload(0);
        xwrite(0, xv);
    }
    half8 bf0[4], bf1[4];
    loadB1(0, bf0);                           // step-0 fragments in flight
    loadB1(1, bf1);
    __syncthreads();

    for (int kt = 0; kt < DIM; kt += 64) {
        const int cur = (kt >> 6) & 1;
        const bool hasNext = (kt + 64 < DIM);
        f32x4 xv;
        if (hasNext) xv = xload(kt + 64);     // issue early: HBM under MFMAs
        const int tkn = (kt >> 5) + 2;        // next step's first k-subtile

        half8 af[4];
#pragma unroll
        for (int mi = 0; mi < 4; ++mi) {
            const _Float16* pa = &xs[cur][((l & 15) + mi * 16) * 64];
            af[mi] = *(const half8*)(pa + (((l >> 4)) ^ (l & 7)) * 8);
        }
        __builtin_amdgcn_s_setprio(1);
#pragma unroll
        for (int mi = 0; mi < 4; ++mi)
#pragma unroll
            for (int ni = 0; ni < 4; ++ni)
                acc[mi][ni] = __builtin_amdgcn_mfma_f32_16x16x32_f16(
                    af[mi], bf0[ni], acc[mi][ni], 0, 0, 0);
        __builtin_amdgcn_s_setprio(0);
        if (hasNext) loadB1(tkn, bf0);        // refill after last use (in flight
                                              // across the barrier below)
#pragma unroll
        for (int mi = 0; mi < 4; ++mi) {
            const _Float16* pa = &xs[cur][((l & 15) + mi * 16) * 64];
            af[mi] = *(const half8*)(pa + ((4 + (l >> 4)) ^ (l & 7)) * 8);
        }
        __builtin_amdgcn_s_setprio(1);
#pragma unroll
        for (int mi = 0; mi < 4; ++mi)
#pragma unroll
            for (int ni = 0; ni < 4; ++ni)
                acc[mi][ni] = __builtin_amdgcn_mfma_f32_16x16x32_f16(
                    af[mi], bf1[ni], acc[mi][ni], 0, 0, 0);
        __builtin_amdgcn_s_setprio(0);
        if (hasNext) loadB1(tkn + 1, bf1);
        __builtin_amdgcn_sched_barrier(0);    // pin cvt+ds_write after MFMAs
        if (hasNext) xwrite(cur ^ 1, xv);
        __syncthreads();
    }

    // ---------------- Phase B (no-max) ----------------
    // e1 = exp2(2*L2E*acc - wsqs[col])   (in place)
    float wq[4];
#pragma unroll
    for (int ni = 0; ni < 4; ++ni) wq[ni] = wsq[w * 64 + ni * 16 + (l & 15)];
#pragma unroll
    for (int mi = 0; mi < 4; ++mi)
#pragma unroll
        for (int ni = 0; ni < 4; ++ni)
#pragma unroll
            for (int q = 0; q < 4; ++q)
                acc[mi][ni][q] = exp2f(fmaf(acc[mi][ni][q], 2.0f * L2E, -wq[ni]));

    // S2 (sum over g2 = {j, l&15}; wave-local) -> reciprocal
    f32x4 rS2[4][2];
#pragma unroll
    for (int mi = 0; mi < 4; ++mi)
#pragma unroll
        for (int p = 0; p < 2; ++p) {
#pragma unroll
            for (int q = 0; q < 4; ++q) {
                float s = acc[mi][2 * p][q] + acc[mi][2 * p + 1][q];
                s += __shfl_xor(s, 1, 64);
                s += __shfl_xor(s, 2, 64);
                s += __shfl_xor(s, 4, 64);
                s += __shfl_xor(s, 8, 64);
                rS2[mi][p][q] = __builtin_amdgcn_rcpf(s);
            }
        }

    // S1 (sum over g1 = {w, p}): one cross-wave LDS round -> 1/S1 in a1_lds
    float* red = (float*)BIG;                 // [16][64][32] swizzled
#pragma unroll
    for (int mi = 0; mi < 4; ++mi)
#pragma unroll
        for (int j = 0; j < 2; ++j)
#pragma unroll
            for (int q = 0; q < 4; ++q) {
                int row = mi * 16 + (l >> 4) * 4 + q;
                red[RIDX(w, row, j * 16 + (l & 15))] =
                    acc[mi][j][q] + acc[mi][2 + j][q];
            }
    __syncthreads();
#pragma unroll
    for (int i = 0; i < 2; ++i) {
        int pr = t + i * 1024;
        int row = pr >> 5, g2 = pr & 31;
        float s = 0.f;
#pragma unroll
        for (int wv = 0; wv < 16; ++wv) s += red[RIDX(wv, row, g2)];
        a1_lds[AIDX(row, g2)] = __builtin_amdgcn_rcpf(s);
    }
    __syncthreads();                          // red dead; BIG becomes cs

    // cu = e1^2 * (1/S1) * (1/S2) -> cs fp16; per-row partial sums
    _Float16* cs = (_Float16*)BIG;            // [64][1024] chunk-swizzled
#pragma unroll
    for (int mi = 0; mi < 4; ++mi) {
        f32x4 rs = {0.f, 0.f, 0.f, 0.f};
#pragma unroll
        for (int j = 0; j < 2; ++j) {
            f32x4 a1v;
#pragma unroll
            for (int q = 0; q < 4; ++q) {
                int row = mi * 16 + (l >> 4) * 4 + q;
                a1v[q] = a1_lds[AIDX(row, j * 16 + (l & 15))];
            }
#pragma unroll
            for (int p = 0; p < 2; ++p) {
                int ni  = 2 * p + j;
                int col = w * 64 + ni * 16 + (l & 15);
                int chunk = col >> 3;
#pragma unroll
                for (int q = 0; q < 4; ++q) {
                    float e = acc[mi][ni][q];
                    float cu = ((e * e) * a1v[q]) * rS2[mi][p][q];
                    rs[q] += cu;
                    int row = mi * 16 + (l >> 4) * 4 + q;
                    cs[row * 1024 + ((chunk ^ (row & 7)) << 3) + (col & 7)] =
                        (_Float16)cu;
                }
            }
        }
#pragma unroll
        for (int q = 0; q < 4; ++q) {
            float sv = rs[q];
            sv += __shfl_xor(sv, 1, 64);
            sv += __shfl_xor(sv, 2, 64);
            sv += __shfl_xor(sv, 4, 64);
            sv += __shfl_xor(sv, 8, 64);
            if ((l & 15) == 0) rowred[w * 64 + mi * 16 + (l >> 4) * 4 + q] = sv;
        }
    }
    __syncthreads();                          // cs + rowred ready

    if (t < 64) {
        float tot = 0.f;
#pragma unroll
        for (int wv = 0; wv < 16; ++wv) tot += rowred[wv * 64 + t];
        rowinv[t] = 1.f / (tot + 1e-8f);
    }

    // ---------------- Phase C: recon = cu @ w (barrier-free K-loop) --------
    // bf reg-double-buffered 2-deep: MFMA(t) never waits on loads of t.
    auto loadB2 = [&](int tn, half8* dst) {
#pragma unroll
        for (int ni = 0; ni < 4; ++ni)
            dst[ni] = *(const half8*)(P2 +
                (((size_t)(w * 4 + ni) * 32 + tn) * 64 + l) * 8);
    };
    auto ldA2 = [&](int tn, half8* dst) {
#pragma unroll
        for (int mi = 0; mi < 4; ++mi) {
            int row = (l & 15) + mi * 16;
            int kc  = tn * 4 + (l >> 4);
            dst[mi] = *(const half8*)(cs + row * 1024 + ((kc ^ (row & 7)) << 3));
        }
    };
    auto mfma16 = [&](f32x4 (&a2)[4][4], half8* af2, half8* bf) {
        __builtin_amdgcn_s_setprio(1);
#pragma unroll
        for (int mi = 0; mi < 4; ++mi)
#pragma unroll
            for (int ni = 0; ni < 4; ++ni)
                a2[mi][ni] = __builtin_amdgcn_mfma_f32_16x16x32_f16(
                    af2[mi], bf[ni], a2[mi][ni], 0, 0, 0);
        __builtin_amdgcn_s_setprio(0);
    };

    f32x4 acc2[4][4] = {};
    half8 bfA[4], bfB[4], af2[4];
    loadB2(0, bfA);
    for (int tn = 0; tn < 32; tn += 2) {
        if (tn + 1 < 32) loadB2(tn + 1, bfB);
        ldA2(tn, af2);
        mfma16(acc2, af2, bfA);
        if (tn + 2 < 32) loadB2(tn + 2, bfA);
        ldA2(tn + 1, af2);
        mfma16(acc2, af2, bfB);
    }
    __syncthreads();                          // rowinv visible to all waves

    // ---------------- epilogue: direct plain stores (L2 merges lines) ------
#pragma unroll
    for (int mi = 0; mi < 4; ++mi)
#pragma unroll
        for (int q = 0; q < 4; ++q) {
            const int rr  = mi * 16 + (l >> 4) * 4 + q;
            const float inv = rowinv[rr];
#pragma unroll
            for (int ni = 0; ni < 4; ++ni) {
                const int col = w * 64 + ni * 16 + (l & 15);
                Out[(size_t)(r0 + rr) * DIM + col] = acc2[mi][ni][q] * inv;
            }
        }
}

// ---------------------------------------------------------------------------
extern "C" void kernel_launch(void* const* d_in, const int* in_sizes, int n_in,
                              void* d_out, int out_size, void* d_ws, size_t ws_size,
                              hipStream_t stream) {
    const float* x = (const float*)d_in[0];        // [16384, 1024] fp32
    const float* w = (const float*)d_in[1];        // [32, 32, 1024] fp32
    float* out = (float*)d_out;                    // [16384, 1024] fp32

    char* ws = (char*)d_ws;
    size_t off = 0;
    _Float16* pack1 = (_Float16*)(ws + off); off += (size_t)NN * DIM * 2;     // 2 MB
    _Float16* pack2 = (_Float16*)(ws + off); off += (size_t)DIM * NN * 2;     // 2 MB
    float*    wsq   = (float*)   (ws + off); off += (size_t)NN * 4;

    prep_pack_kernel<<<512, 256, 0, stream>>>(w, pack1, pack2);
    wsq_kernel<<<NN, 256, 0, stream>>>(w, wsq);
    fused_som_kernel<<<BATCH / 64, 1024, 0, stream>>>(x, pack1, pack2, wsq, out);
}

// Round 6
// 261.499 us; speedup vs baseline: 1.0337x; 1.0337x over previous
//
#include <hip/hip_runtime.h>

// Problem constants
static constexpr int BATCH = 16384;   // rows of x
static constexpr int DIM   = 1024;    // feature dim
static constexpr int NN    = 1024;    // 32*32 grid nodes

typedef _Float16 half8  __attribute__((ext_vector_type(8)));
typedef _Float16 half4v __attribute__((ext_vector_type(4)));
typedef float    f32x4  __attribute__((ext_vector_type(4)));

static constexpr float L2E = 1.44269504088896340736f;

// ---------------------------------------------------------------------------
// prep 1: pack W into MFMA-fragment-major fp16 layout for both GEMMs.
// Fragment (16x16x32 f16 B-operand): lane l supplies
//   B[t_n*16 + (l&15)][t_k*32 + (l>>4)*8 + j], j=0..7  (one half8).
// P1[f=(t_n*32+t_k)][l][8] : B = w[n][d]    (GEMM1: S = x @ w^T)
// P2[f=(t_d*32+t_n)][l][8] : B = w[n][d]^T  (GEMM2: recon = c @ w)
// ---------------------------------------------------------------------------
__global__ __launch_bounds__(256) void prep_pack_kernel(const float* __restrict__ W,
                                                        _Float16* __restrict__ P1,
                                                        _Float16* __restrict__ P2) {
    const int l = threadIdx.x & 63;
    const int v = threadIdx.x >> 6;
    const int f = blockIdx.x * 4 + v;          // 0..2047
    const int hi = f >> 5, lo = f & 31;
    {   // P1: n-tile = hi, k(d)-tile = lo
        int n  = hi * 16 + (l & 15);
        int k0 = lo * 32 + (l >> 4) * 8;
        const float* src = W + (size_t)n * DIM + k0;
        f32x4 a = *(const f32x4*)src;
        f32x4 b = *(const f32x4*)(src + 4);
        half8 h;
#pragma unroll
        for (int q = 0; q < 4; ++q) { h[q] = (_Float16)a[q]; h[4 + q] = (_Float16)b[q]; }
        *(half8*)(P1 + ((size_t)f * 64 + l) * 8) = h;
    }
    {   // P2: d-tile = hi, k(n)-tile = lo
        int d  = hi * 16 + (l & 15);
        int n0 = lo * 32 + (l >> 4) * 8;
        half8 h;
#pragma unroll
        for (int j = 0; j < 8; ++j) h[j] = (_Float16)W[(size_t)(n0 + j) * DIM + d];
        *(half8*)(P2 + ((size_t)f * 64 + l) * 8) = h;
    }
}

// ---------------------------------------------------------------------------
// prep 2: wsqs[n] = L2E * ||w_n||^2   (pre-scaled for exp2 argument folding)
// ---------------------------------------------------------------------------
__global__ __launch_bounds__(256) void wsq_kernel(const float* __restrict__ W,
                                                  float* __restrict__ wsq) {
    const int n = blockIdx.x;
    const int t = threadIdx.x;
    float4 v = *(const float4*)(W + (size_t)n * DIM + 4 * t);
    float ss = v.x * v.x + v.y * v.y + v.z * v.z + v.w * v.w;
#pragma unroll
    for (int o = 32; o > 0; o >>= 1) ss += __shfl_xor(ss, o, 64);
    __shared__ float red[4];
    if ((t & 63) == 0) red[t >> 6] = ss;
    __syncthreads();
    if (t == 0) wsq[n] = L2E * (red[0] + red[1] + red[2] + red[3]);
}

// ---------------------------------------------------------------------------
// FUSED: per block = 64 rows of x.  16 waves x 1024 threads, 256 blocks.
// Wave w owns cols w*64 + ni*16 + (l&15), ni=0..3.
//   Phase A: raw dot acc = x@w^T in regs; x fp32 loaded to regs (nt), cvt
//            fp16, ds_write into xs dbuf.  P1 fragments software-pipelined
//            ACROSS the per-step barrier (in-place reg reuse; T4-style).
//   Phase B (NO-MAX softmax; logits v = 2*acc - wsq lie in ~[-21,18]):
//            e1 = exp2(2*L2E*acc - wsqs[col]); S2 wave-local (shfl), S1
//            cross-wave via one swizzled-LDS round; cu = e1^2*rcp(S1)*rcp(S2)
//            -> cs fp16 (row-unnormalized).
//   Phase C: recon = cu @ w, barrier-free K-loop; bf reg-double-buffered.
//   Epilogue: row-normalize, stage through LDS, PLAIN f32x4 full-line stores
//            (8 lanes x 16B = one 128B line; no RMW, no nt 16B-granule writes;
//            round-5 lesson: plain scattered 4B stores => +71MB RMW FETCH,
//            306MB WRITE; nt scattered => 2x; nt full-line => 1.5x).
// Element map: row = mi*16+(l>>4)*4+q; col n = w*64+ni*16+(l&15);
//   g1 = n>>5 = w*2+(ni>>1) [p];  g2 = n&31 = (ni&1)*16+(l&15) [j].
// LDS: xs 16K + BIG 128K (red/cs/stg union) + a1 8K + rowred 4K + rowinv.
// ---------------------------------------------------------------------------
__global__ __launch_bounds__(1024, 4) void fused_som_kernel(
    const float* __restrict__ X, const _Float16* __restrict__ P1,
    const _Float16* __restrict__ P2, const float* __restrict__ wsq,
    float* __restrict__ Out) {

    __shared__ __align__(16) _Float16 xs[2][64 * 64];   // 16 KB dbuf
    __shared__ __align__(16) char     BIG[131072];      // red / cs / stg union
    __shared__ __align__(16) float    a1_lds[64 * 32];  // 8 KB (stores 1/S1)
    __shared__ __align__(16) float    rowred[16 * 64];  // 4 KB
    __shared__ __align__(16) float    rowinv[64];

    const int t  = threadIdx.x;
    const int l  = t & 63;
    const int w  = t >> 6;
    const int r0 = blockIdx.x * 64;

    // swizzled index helpers (2-way max bank aliasing for cross-wave reduce)
    auto RIDX = [](int wv, int row, int g2) {
        return (wv * 64 + row) * 32 + (g2 ^ ((row & 4) << 2));
    };
    auto AIDX = [](int row, int g2) {
        return row * 32 + (g2 ^ ((row & 4) << 2));
    };

    // ---------------- Phase A ----------------
    const int srow = t >> 4;                  // staging row 0..63
    const int skq  = t & 15;                  // f32x4 index within 64-k tile

    auto xload = [&](int kt) -> f32x4 {
        return __builtin_nontemporal_load(
            (const f32x4*)(X + (size_t)(r0 + srow) * DIM + kt + skq * 4));
    };
    auto xwrite = [&](int buf, f32x4 v) {
        half4v h;
        h[0] = (_Float16)v[0]; h[1] = (_Float16)v[1];
        h[2] = (_Float16)v[2]; h[3] = (_Float16)v[3];
        int c = skq >> 1;                     // 16-B chunk 0..7
        *(half4v*)&xs[buf][srow * 64 + ((c ^ (srow & 7)) << 3) + ((skq & 1) << 2)] = h;
    };
    // P1 fragment loads for one 32-k subtile (pure global; no LDS dep)
    auto loadB1 = [&](int tk, half8* dst) {
#pragma unroll
        for (int ni = 0; ni < 4; ++ni)
            dst[ni] = *(const half8*)(P1 +
                (((size_t)(w * 4 + ni) * 32 + tk) * 64 + l) * 8);
    };

    f32x4 acc[4][4] = {};
    {   // prologue: tile 0 -> xs[0]
        f32x4 xv = xload(0);
        xwrite(0, xv);
    }
    half8 bf0[4], bf1[4];
    loadB1(0, bf0);                           // step-0 fragments in flight
    loadB1(1, bf1);
    __syncthreads();

    for (int kt = 0; kt < DIM; kt += 64) {
        const int cur = (kt >> 6) & 1;
        const bool hasNext = (kt + 64 < DIM);
        f32x4 xv;
        if (hasNext) xv = xload(kt + 64);     // issue early: HBM under MFMAs
        const int tkn = (kt >> 5) + 2;        // next step's first k-subtile

        half8 af[4];
#pragma unroll
        for (int mi = 0; mi < 4; ++mi) {
            const _Float16* pa = &xs[cur][((l & 15) + mi * 16) * 64];
            af[mi] = *(const half8*)(pa + (((l >> 4)) ^ (l & 7)) * 8);
        }
        __builtin_amdgcn_s_setprio(1);
#pragma unroll
        for (int mi = 0; mi < 4; ++mi)
#pragma unroll
            for (int ni = 0; ni < 4; ++ni)
                acc[mi][ni] = __builtin_amdgcn_mfma_f32_16x16x32_f16(
                    af[mi], bf0[ni], acc[mi][ni], 0, 0, 0);
        __builtin_amdgcn_s_setprio(0);
        if (hasNext) loadB1(tkn, bf0);        // refill after last use (in flight
                                              // across the barrier below)
#pragma unroll
        for (int mi = 0; mi < 4; ++mi) {
            const _Float16* pa = &xs[cur][((l & 15) + mi * 16) * 64];
            af[mi] = *(const half8*)(pa + ((4 + (l >> 4)) ^ (l & 7)) * 8);
        }
        __builtin_amdgcn_s_setprio(1);
#pragma unroll
        for (int mi = 0; mi < 4; ++mi)
#pragma unroll
            for (int ni = 0; ni < 4; ++ni)
                acc[mi][ni] = __builtin_amdgcn_mfma_f32_16x16x32_f16(
                    af[mi], bf1[ni], acc[mi][ni], 0, 0, 0);
        __builtin_amdgcn_s_setprio(0);
        if (hasNext) loadB1(tkn + 1, bf1);
        __builtin_amdgcn_sched_barrier(0);    // pin cvt+ds_write after MFMAs
        if (hasNext) xwrite(cur ^ 1, xv);
        __syncthreads();
    }

    // ---------------- Phase B (no-max) ----------------
    // e1 = exp2(2*L2E*acc - wsqs[col])   (in place)
    float wq[4];
#pragma unroll
    for (int ni = 0; ni < 4; ++ni) wq[ni] = wsq[w * 64 + ni * 16 + (l & 15)];
#pragma unroll
    for (int mi = 0; mi < 4; ++mi)
#pragma unroll
        for (int ni = 0; ni < 4; ++ni)
#pragma unroll
            for (int q = 0; q < 4; ++q)
                acc[mi][ni][q] = exp2f(fmaf(acc[mi][ni][q], 2.0f * L2E, -wq[ni]));

    // S2 (sum over g2 = {j, l&15}; wave-local) -> reciprocal
    f32x4 rS2[4][2];
#pragma unroll
    for (int mi = 0; mi < 4; ++mi)
#pragma unroll
        for (int p = 0; p < 2; ++p) {
#pragma unroll
            for (int q = 0; q < 4; ++q) {
                float s = acc[mi][2 * p][q] + acc[mi][2 * p + 1][q];
                s += __shfl_xor(s, 1, 64);
                s += __shfl_xor(s, 2, 64);
                s += __shfl_xor(s, 4, 64);
                s += __shfl_xor(s, 8, 64);
                rS2[mi][p][q] = __builtin_amdgcn_rcpf(s);
            }
        }

    // S1 (sum over g1 = {w, p}): one cross-wave LDS round -> 1/S1 in a1_lds
    float* red = (float*)BIG;                 // [16][64][32] swizzled
#pragma unroll
    for (int mi = 0; mi < 4; ++mi)
#pragma unroll
        for (int j = 0; j < 2; ++j)
#pragma unroll
            for (int q = 0; q < 4; ++q) {
                int row = mi * 16 + (l >> 4) * 4 + q;
                red[RIDX(w, row, j * 16 + (l & 15))] =
                    acc[mi][j][q] + acc[mi][2 + j][q];
            }
    __syncthreads();
#pragma unroll
    for (int i = 0; i < 2; ++i) {
        int pr = t + i * 1024;
        int row = pr >> 5, g2 = pr & 31;
        float s = 0.f;
#pragma unroll
        for (int wv = 0; wv < 16; ++wv) s += red[RIDX(wv, row, g2)];
        a1_lds[AIDX(row, g2)] = __builtin_amdgcn_rcpf(s);
    }
    __syncthreads();                          // red dead; BIG becomes cs

    // cu = e1^2 * (1/S1) * (1/S2) -> cs fp16; per-row partial sums
    _Float16* cs = (_Float16*)BIG;            // [64][1024] chunk-swizzled
#pragma unroll
    for (int mi = 0; mi < 4; ++mi) {
        f32x4 rs = {0.f, 0.f, 0.f, 0.f};
#pragma unroll
        for (int j = 0; j < 2; ++j) {
            f32x4 a1v;
#pragma unroll
            for (int q = 0; q < 4; ++q) {
                int row = mi * 16 + (l >> 4) * 4 + q;
                a1v[q] = a1_lds[AIDX(row, j * 16 + (l & 15))];
            }
#pragma unroll
            for (int p = 0; p < 2; ++p) {
                int ni  = 2 * p + j;
                int col = w * 64 + ni * 16 + (l & 15);
                int chunk = col >> 3;
#pragma unroll
                for (int q = 0; q < 4; ++q) {
                    float e = acc[mi][ni][q];
                    float cu = ((e * e) * a1v[q]) * rS2[mi][p][q];
                    rs[q] += cu;
                    int row = mi * 16 + (l >> 4) * 4 + q;
                    cs[row * 1024 + ((chunk ^ (row & 7)) << 3) + (col & 7)] =
                        (_Float16)cu;
                }
            }
        }
#pragma unroll
        for (int q = 0; q < 4; ++q) {
            float sv = rs[q];
            sv += __shfl_xor(sv, 1, 64);
            sv += __shfl_xor(sv, 2, 64);
            sv += __shfl_xor(sv, 4, 64);
            sv += __shfl_xor(sv, 8, 64);
            if ((l & 15) == 0) rowred[w * 64 + mi * 16 + (l >> 4) * 4 + q] = sv;
        }
    }
    __syncthreads();                          // cs + rowred ready

    if (t < 64) {
        float tot = 0.f;
#pragma unroll
        for (int wv = 0; wv < 16; ++wv) tot += rowred[wv * 64 + t];
        rowinv[t] = 1.f / (tot + 1e-8f);
    }

    // ---------------- Phase C: recon = cu @ w (barrier-free K-loop) --------
    // bf reg-double-buffered 2-deep: MFMA(t) never waits on loads of t.
    auto loadB2 = [&](int tn, half8* dst) {
#pragma unroll
        for (int ni = 0; ni < 4; ++ni)
            dst[ni] = *(const half8*)(P2 +
                (((size_t)(w * 4 + ni) * 32 + tn) * 64 + l) * 8);
    };
    auto ldA2 = [&](int tn, half8* dst) {
#pragma unroll
        for (int mi = 0; mi < 4; ++mi) {
            int row = (l & 15) + mi * 16;
            int kc  = tn * 4 + (l >> 4);
            dst[mi] = *(const half8*)(cs + row * 1024 + ((kc ^ (row & 7)) << 3));
        }
    };
    auto mfma16 = [&](f32x4 (&a2)[4][4], half8* af2, half8* bf) {
        __builtin_amdgcn_s_setprio(1);
#pragma unroll
        for (int mi = 0; mi < 4; ++mi)
#pragma unroll
            for (int ni = 0; ni < 4; ++ni)
                a2[mi][ni] = __builtin_amdgcn_mfma_f32_16x16x32_f16(
                    af2[mi], bf[ni], a2[mi][ni], 0, 0, 0);
        __builtin_amdgcn_s_setprio(0);
    };

    f32x4 acc2[4][4] = {};
    half8 bfA[4], bfB[4], af2[4];
    loadB2(0, bfA);
    for (int tn = 0; tn < 32; tn += 2) {
        if (tn + 1 < 32) loadB2(tn + 1, bfB);
        ldA2(tn, af2);
        mfma16(acc2, af2, bfA);
        if (tn + 2 < 32) loadB2(tn + 2, bfA);
        ldA2(tn + 1, af2);
        mfma16(acc2, af2, bfB);
    }

    // ---------------- epilogue: LDS-staged full-line PLAIN stores ----------
    __syncthreads();                          // cs reads done; rowinv visible
    float* stg = (float*)BIG;                 // [32][1024] f32, col-swizzled
#pragma unroll
    for (int half = 0; half < 2; ++half) {
        if (half) __syncthreads();            // previous read round done
#pragma unroll
        for (int mm = 0; mm < 2; ++mm) {
            const int mi = half * 2 + mm;
#pragma unroll
            for (int ni = 0; ni < 4; ++ni) {
                const int col = w * 64 + ni * 16 + (l & 15);
#pragma unroll
                for (int q = 0; q < 4; ++q) {
                    const int rr = (l >> 4) * 4 + q;          // 0..15
                    const float inv = rowinv[mi * 16 + rr];
                    stg[(mm * 16 + rr) * 1024 + (col ^ ((rr & 4) << 2))] =
                        acc2[mi][ni][q] * inv;
                }
            }
        }
        __syncthreads();
#pragma unroll
        for (int i = 0; i < 8; ++i) {
            const int c  = t + i * 1024;      // 8192 f32x4 chunks
            const int rr = c >> 8;            // 0..31
            const int c4 = c & 255;
            f32x4 v = *(const f32x4*)&stg[rr * 1024 + ((c4 * 4) ^ ((rr & 4) << 2))];
            *(f32x4*)(Out + (size_t)(r0 + half * 32 + rr) * DIM + c4 * 4) = v;
        }
    }
}

// ---------------------------------------------------------------------------
extern "C" void kernel_launch(void* const* d_in, const int* in_sizes, int n_in,
                              void* d_out, int out_size, void* d_ws, size_t ws_size,
                              hipStream_t stream) {
    const float* x = (const float*)d_in[0];        // [16384, 1024] fp32
    const float* w = (const float*)d_in[1];        // [32, 32, 1024] fp32
    float* out = (float*)d_out;                    // [16384, 1024] fp32

    char* ws = (char*)d_ws;
    size_t off = 0;
    _Float16* pack1 = (_Float16*)(ws + off); off += (size_t)NN * DIM * 2;     // 2 MB
    _Float16* pack2 = (_Float16*)(ws + off); off += (size_t)DIM * NN * 2;     // 2 MB
    float*    wsq   = (float*)   (ws + off); off += (size_t)NN * 4;

    prep_pack_kernel<<<512, 256, 0, stream>>>(w, pack1, pack2);
    wsq_kernel<<<NN, 256, 0, stream>>>(w, wsq);
    fused_som_kernel<<<BATCH / 64, 1024, 0, stream>>>(x, pack1, pack2, wsq, out);
}

// Round 7
// 260.852 us; speedup vs baseline: 1.0362x; 1.0025x over previous
//
#include <hip/hip_runtime.h>

// Problem constants
static constexpr int BATCH = 16384;   // rows of x
static constexpr int DIM   = 1024;    // feature dim
static constexpr int NN    = 1024;    // 32*32 grid nodes

typedef _Float16 half8  __attribute__((ext_vector_type(8)));
typedef _Float16 half4v __attribute__((ext_vector_type(4)));
typedef float    f32x4  __attribute__((ext_vector_type(4)));

static constexpr float L2E = 1.44269504088896340736f;

// ---------------------------------------------------------------------------
// prep 1: pack W into MFMA-fragment-major fp16 layout for both GEMMs.
// Fragment (16x16x32 f16 B-operand): lane l supplies
//   B[t_n*16 + (l&15)][t_k*32 + (l>>4)*8 + j], j=0..7  (one half8).
// P1[f=(t_n*32+t_k)][l][8] : B = w[n][d]    (GEMM1: S = x @ w^T)
// P2[f=(t_d*32+t_n)][l][8] : B = w[n][d]^T  (GEMM2: recon = c @ w)
// ---------------------------------------------------------------------------
__global__ __launch_bounds__(256) void prep_pack_kernel(const float* __restrict__ W,
                                                        _Float16* __restrict__ P1,
                                                        _Float16* __restrict__ P2) {
    const int l = threadIdx.x & 63;
    const int v = threadIdx.x >> 6;
    const int f = blockIdx.x * 4 + v;          // 0..2047
    const int hi = f >> 5, lo = f & 31;
    {   // P1: n-tile = hi, k(d)-tile = lo
        int n  = hi * 16 + (l & 15);
        int k0 = lo * 32 + (l >> 4) * 8;
        const float* src = W + (size_t)n * DIM + k0;
        f32x4 a = *(const f32x4*)src;
        f32x4 b = *(const f32x4*)(src + 4);
        half8 h;
#pragma unroll
        for (int q = 0; q < 4; ++q) { h[q] = (_Float16)a[q]; h[4 + q] = (_Float16)b[q]; }
        *(half8*)(P1 + ((size_t)f * 64 + l) * 8) = h;
    }
    {   // P2: d-tile = hi, k(n)-tile = lo
        int d  = hi * 16 + (l & 15);
        int n0 = lo * 32 + (l >> 4) * 8;
        half8 h;
#pragma unroll
        for (int j = 0; j < 8; ++j) h[j] = (_Float16)W[(size_t)(n0 + j) * DIM + d];
        *(half8*)(P2 + ((size_t)f * 64 + l) * 8) = h;
    }
}

// ---------------------------------------------------------------------------
// prep 2: wsqs[n] = L2E * ||w_n||^2   (pre-scaled for exp2 argument folding)
// ---------------------------------------------------------------------------
__global__ __launch_bounds__(256) void wsq_kernel(const float* __restrict__ W,
                                                  float* __restrict__ wsq) {
    const int n = blockIdx.x;
    const int t = threadIdx.x;
    float4 v = *(const float4*)(W + (size_t)n * DIM + 4 * t);
    float ss = v.x * v.x + v.y * v.y + v.z * v.z + v.w * v.w;
#pragma unroll
    for (int o = 32; o > 0; o >>= 1) ss += __shfl_xor(ss, o, 64);
    __shared__ float red[4];
    if ((t & 63) == 0) red[t >> 6] = ss;
    __syncthreads();
    if (t == 0) wsq[n] = L2E * (red[0] + red[1] + red[2] + red[3]);
}

// ---------------------------------------------------------------------------
// FUSED: per block = 64 rows of x.  16 waves x 1024 threads, 256 blocks.
// Wave w owns cols w*64 + ni*16 + (l&15), ni=0..3.
// RULE-#20 NOTE: all MFMA fragment arrays (bf0/bf1/bfA/bfB/af/af2) are filled
// by DIRECT constant-indexed unrolled loops — never passed through lambda /
// pointer args.  Round 5/6 used half8* lambda params and the arrays went to
// scratch: +73MB FETCH, +194MB WRITE, +58us (vs round 4's direct code).
//   Phase A: raw dot acc = x@w^T in regs; x fp32 -> regs (nt), cvt fp16,
//            ds_write into xs dbuf.  P1 fragments refilled right after last
//            use, staying in flight ACROSS the barrier (T4-style).
//   Phase B (NO-MAX softmax; logits v = 2*acc - wsq lie in ~[-21,18]):
//            e1 = exp2(2*L2E*acc - wsqs[col]); S2 wave-local (shfl), S1
//            cross-wave via one swizzled-LDS round; cu = e1^2*rcp(S1)*rcp(S2)
//            -> cs fp16 (row-unnormalized).
//   Phase C: recon = cu @ w, barrier-free K-loop; bf reg-double-buffered.
//   Epilogue: row-normalize, stage through LDS, PLAIN f32x4 full-line stores.
// Element map: row = mi*16+(l>>4)*4+q; col n = w*64+ni*16+(l&15);
//   g1 = n>>5 = w*2+(ni>>1) [p];  g2 = n&31 = (ni&1)*16+(l&15) [j].
// LDS: xs 16K + BIG 128K (red/cs/stg union) + a1 8K + rowred 4K + rowinv.
// ---------------------------------------------------------------------------
__global__ __launch_bounds__(1024, 4) void fused_som_kernel(
    const float* __restrict__ X, const _Float16* __restrict__ P1,
    const _Float16* __restrict__ P2, const float* __restrict__ wsq,
    float* __restrict__ Out) {

    __shared__ __align__(16) _Float16 xs[2][64 * 64];   // 16 KB dbuf
    __shared__ __align__(16) char     BIG[131072];      // red / cs / stg union
    __shared__ __align__(16) float    a1_lds[64 * 32];  // 8 KB (stores 1/S1)
    __shared__ __align__(16) float    rowred[16 * 64];  // 4 KB
    __shared__ __align__(16) float    rowinv[64];

    const int t  = threadIdx.x;
    const int l  = t & 63;
    const int w  = t >> 6;
    const int r0 = blockIdx.x * 64;

    // swizzled index helpers (scalar in/out only — safe)
    auto RIDX = [](int wv, int row, int g2) {
        return (wv * 64 + row) * 32 + (g2 ^ ((row & 4) << 2));
    };
    auto AIDX = [](int row, int g2) {
        return row * 32 + (g2 ^ ((row & 4) << 2));
    };

    // ---------------- Phase A ----------------
    const int srow = t >> 4;                  // staging row 0..63
    const int skq  = t & 15;                  // f32x4 index within 64-k tile

    auto xload = [&](int kt) -> f32x4 {       // by-value return — safe
        return __builtin_nontemporal_load(
            (const f32x4*)(X + (size_t)(r0 + srow) * DIM + kt + skq * 4));
    };
    auto xwrite = [&](int buf, f32x4 v) {     // by-value arg — safe
        half4v h;
        h[0] = (_Float16)v[0]; h[1] = (_Float16)v[1];
        h[2] = (_Float16)v[2]; h[3] = (_Float16)v[3];
        int c = skq >> 1;                     // 16-B chunk 0..7
        *(half4v*)&xs[buf][srow * 64 + ((c ^ (srow & 7)) << 3) + ((skq & 1) << 2)] = h;
    };

    f32x4 acc[4][4] = {};
    {   // prologue: tile 0 -> xs[0]
        f32x4 xv = xload(0);
        xwrite(0, xv);
    }
    half8 bf0[4], bf1[4];
#pragma unroll
    for (int ni = 0; ni < 4; ++ni) {          // step-0 fragments in flight
        bf0[ni] = *(const half8*)(P1 + (((size_t)(w * 4 + ni) * 32 + 0) * 64 + l) * 8);
        bf1[ni] = *(const half8*)(P1 + (((size_t)(w * 4 + ni) * 32 + 1) * 64 + l) * 8);
    }
    __syncthreads();

    for (int kt = 0; kt < DIM; kt += 64) {
        const int cur = (kt >> 6) & 1;
        const bool hasNext = (kt + 64 < DIM);
        f32x4 xv;
        if (hasNext) xv = xload(kt + 64);     // issue early: HBM under MFMAs
        const int tkn = (kt >> 5) + 2;        // next step's first k-subtile

        half8 af[4];
#pragma unroll
        for (int mi = 0; mi < 4; ++mi) {
            const _Float16* pa = &xs[cur][((l & 15) + mi * 16) * 64];
            af[mi] = *(const half8*)(pa + (((l >> 4)) ^ (l & 7)) * 8);
        }
        __builtin_amdgcn_s_setprio(1);
#pragma unroll
        for (int mi = 0; mi < 4; ++mi)
#pragma unroll
            for (int ni = 0; ni < 4; ++ni)
                acc[mi][ni] = __builtin_amdgcn_mfma_f32_16x16x32_f16(
                    af[mi], bf0[ni], acc[mi][ni], 0, 0, 0);
        __builtin_amdgcn_s_setprio(0);
        if (hasNext) {                        // refill after last use; stays in
#pragma unroll                                // flight across the barrier below
            for (int ni = 0; ni < 4; ++ni)
                bf0[ni] = *(const half8*)(P1 +
                    (((size_t)(w * 4 + ni) * 32 + tkn) * 64 + l) * 8);
        }
#pragma unroll
        for (int mi = 0; mi < 4; ++mi) {
            const _Float16* pa = &xs[cur][((l & 15) + mi * 16) * 64];
            af[mi] = *(const half8*)(pa + ((4 + (l >> 4)) ^ (l & 7)) * 8);
        }
        __builtin_amdgcn_s_setprio(1);
#pragma unroll
        for (int mi = 0; mi < 4; ++mi)
#pragma unroll
            for (int ni = 0; ni < 4; ++ni)
                acc[mi][ni] = __builtin_amdgcn_mfma_f32_16x16x32_f16(
                    af[mi], bf1[ni], acc[mi][ni], 0, 0, 0);
        __builtin_amdgcn_s_setprio(0);
        if (hasNext) {
#pragma unroll
            for (int ni = 0; ni < 4; ++ni)
                bf1[ni] = *(const half8*)(P1 +
                    (((size_t)(w * 4 + ni) * 32 + tkn + 1) * 64 + l) * 8);
        }
        __builtin_amdgcn_sched_barrier(0);    // pin cvt+ds_write after MFMAs
        if (hasNext) xwrite(cur ^ 1, xv);
        __syncthreads();
    }

    // ---------------- Phase B (no-max) ----------------
    // e1 = exp2(2*L2E*acc - wsqs[col])   (in place)
    float wq[4];
#pragma unroll
    for (int ni = 0; ni < 4; ++ni) wq[ni] = wsq[w * 64 + ni * 16 + (l & 15)];
#pragma unroll
    for (int mi = 0; mi < 4; ++mi)
#pragma unroll
        for (int ni = 0; ni < 4; ++ni)
#pragma unroll
            for (int q = 0; q < 4; ++q)
                acc[mi][ni][q] = exp2f(fmaf(acc[mi][ni][q], 2.0f * L2E, -wq[ni]));

    // S2 (sum over g2 = {j, l&15}; wave-local) -> reciprocal
    f32x4 rS2[4][2];
#pragma unroll
    for (int mi = 0; mi < 4; ++mi)
#pragma unroll
        for (int p = 0; p < 2; ++p) {
#pragma unroll
            for (int q = 0; q < 4; ++q) {
                float s = acc[mi][2 * p][q] + acc[mi][2 * p + 1][q];
                s += __shfl_xor(s, 1, 64);
                s += __shfl_xor(s, 2, 64);
                s += __shfl_xor(s, 4, 64);
                s += __shfl_xor(s, 8, 64);
                rS2[mi][p][q] = __builtin_amdgcn_rcpf(s);
            }
        }

    // S1 (sum over g1 = {w, p}): one cross-wave LDS round -> 1/S1 in a1_lds
    float* red = (float*)BIG;                 // [16][64][32] swizzled
#pragma unroll
    for (int mi = 0; mi < 4; ++mi)
#pragma unroll
        for (int j = 0; j < 2; ++j)
#pragma unroll
            for (int q = 0; q < 4; ++q) {
                int row = mi * 16 + (l >> 4) * 4 + q;
                red[RIDX(w, row, j * 16 + (l & 15))] =
                    acc[mi][j][q] + acc[mi][2 + j][q];
            }
    __syncthreads();
#pragma unroll
    for (int i = 0; i < 2; ++i) {
        int pr = t + i * 1024;
        int row = pr >> 5, g2 = pr & 31;
        float s = 0.f;
#pragma unroll
        for (int wv = 0; wv < 16; ++wv) s += red[RIDX(wv, row, g2)];
        a1_lds[AIDX(row, g2)] = __builtin_amdgcn_rcpf(s);
    }
    __syncthreads();                          // red dead; BIG becomes cs

    // cu = e1^2 * (1/S1) * (1/S2) -> cs fp16; per-row partial sums
    _Float16* cs = (_Float16*)BIG;            // [64][1024] chunk-swizzled
#pragma unroll
    for (int mi = 0; mi < 4; ++mi) {
        f32x4 rs = {0.f, 0.f, 0.f, 0.f};
#pragma unroll
        for (int j = 0; j < 2; ++j) {
            f32x4 a1v;
#pragma unroll
            for (int q = 0; q < 4; ++q) {
                int row = mi * 16 + (l >> 4) * 4 + q;
                a1v[q] = a1_lds[AIDX(row, j * 16 + (l & 15))];
            }
#pragma unroll
            for (int p = 0; p < 2; ++p) {
                int ni  = 2 * p + j;
                int col = w * 64 + ni * 16 + (l & 15);
                int chunk = col >> 3;
#pragma unroll
                for (int q = 0; q < 4; ++q) {
                    float e = acc[mi][ni][q];
                    float cu = ((e * e) * a1v[q]) * rS2[mi][p][q];
                    rs[q] += cu;
                    int row = mi * 16 + (l >> 4) * 4 + q;
                    cs[row * 1024 + ((chunk ^ (row & 7)) << 3) + (col & 7)] =
                        (_Float16)cu;
                }
            }
        }
#pragma unroll
        for (int q = 0; q < 4; ++q) {
            float sv = rs[q];
            sv += __shfl_xor(sv, 1, 64);
            sv += __shfl_xor(sv, 2, 64);
            sv += __shfl_xor(sv, 4, 64);
            sv += __shfl_xor(sv, 8, 64);
            if ((l & 15) == 0) rowred[w * 64 + mi * 16 + (l >> 4) * 4 + q] = sv;
        }
    }
    __syncthreads();                          // cs + rowred ready

    if (t < 64) {
        float tot = 0.f;
#pragma unroll
        for (int wv = 0; wv < 16; ++wv) tot += rowred[wv * 64 + t];
        rowinv[t] = 1.f / (tot + 1e-8f);
    }

    // ---------------- Phase C: recon = cu @ w (barrier-free K-loop) --------
    // bf reg-double-buffered 2-deep; all direct constant-indexed code.
    f32x4 acc2[4][4] = {};
    half8 bfA[4], bfB[4], af2[4];
#pragma unroll
    for (int ni = 0; ni < 4; ++ni)
        bfA[ni] = *(const half8*)(P2 + (((size_t)(w * 4 + ni) * 32 + 0) * 64 + l) * 8);

    for (int tn = 0; tn < 32; tn += 2) {
        if (tn + 1 < 32) {
#pragma unroll
            for (int ni = 0; ni < 4; ++ni)
                bfB[ni] = *(const half8*)(P2 +
                    (((size_t)(w * 4 + ni) * 32 + tn + 1) * 64 + l) * 8);
        }
#pragma unroll
        for (int mi = 0; mi < 4; ++mi) {
            int row = (l & 15) + mi * 16;
            int kc  = tn * 4 + (l >> 4);
            af2[mi] = *(const half8*)(cs + row * 1024 + ((kc ^ (row & 7)) << 3));
        }
        __builtin_amdgcn_s_setprio(1);
#pragma unroll
        for (int mi = 0; mi < 4; ++mi)
#pragma unroll
            for (int ni = 0; ni < 4; ++ni)
                acc2[mi][ni] = __builtin_amdgcn_mfma_f32_16x16x32_f16(
                    af2[mi], bfA[ni], acc2[mi][ni], 0, 0, 0);
        __builtin_amdgcn_s_setprio(0);
        if (tn + 2 < 32) {
#pragma unroll
            for (int ni = 0; ni < 4; ++ni)
                bfA[ni] = *(const half8*)(P2 +
                    (((size_t)(w * 4 + ni) * 32 + tn + 2) * 64 + l) * 8);
        }
#pragma unroll
        for (int mi = 0; mi < 4; ++mi) {
            int row = (l & 15) + mi * 16;
            int kc  = (tn + 1) * 4 + (l >> 4);
            af2[mi] = *(const half8*)(cs + row * 1024 + ((kc ^ (row & 7)) << 3));
        }
        __builtin_amdgcn_s_setprio(1);
#pragma unroll
        for (int mi = 0; mi < 4; ++mi)
#pragma unroll
            for (int ni = 0; ni < 4; ++ni)
                acc2[mi][ni] = __builtin_amdgcn_mfma_f32_16x16x32_f16(
                    af2[mi], bfB[ni], acc2[mi][ni], 0, 0, 0);
        __builtin_amdgcn_s_setprio(0);
    }

    // ---------------- epilogue: LDS-staged full-line PLAIN stores ----------
    __syncthreads();                          // cs reads done; rowinv visible
    float* stg = (float*)BIG;                 // [32][1024] f32, col-swizzled
#pragma unroll
    for (int half = 0; half < 2; ++half) {
        if (half) __syncthreads();            // previous read round done
#pragma unroll
        for (int mm = 0; mm < 2; ++mm) {
            const int mi = half * 2 + mm;
#pragma unroll
            for (int ni = 0; ni < 4; ++ni) {
                const int col = w * 64 + ni * 16 + (l & 15);
#pragma unroll
                for (int q = 0; q < 4; ++q) {
                    const int rr = (l >> 4) * 4 + q;          // 0..15
                    const float inv = rowinv[mi * 16 + rr];
                    stg[(mm * 16 + rr) * 1024 + (col ^ ((rr & 4) << 2))] =
                        acc2[mi][ni][q] * inv;
                }
            }
        }
        __syncthreads();
#pragma unroll
        for (int i = 0; i < 8; ++i) {
            const int c  = t + i * 1024;      // 8192 f32x4 chunks
            const int rr = c >> 8;            // 0..31
            const int c4 = c & 255;
            f32x4 v = *(const f32x4*)&stg[rr * 1024 + ((c4 * 4) ^ ((rr & 4) << 2))];
            *(f32x4*)(Out + (size_t)(r0 + half * 32 + rr) * DIM + c4 * 4) = v;
        }
    }
}

// ---------------------------------------------------------------------------
extern "C" void kernel_launch(void* const* d_in, const int* in_sizes, int n_in,
                              void* d_out, int out_size, void* d_ws, size_t ws_size,
                              hipStream_t stream) {
    const float* x = (const float*)d_in[0];        // [16384, 1024] fp32
    const float* w = (const float*)d_in[1];        // [32, 32, 1024] fp32
    float* out = (float*)d_out;                    // [16384, 1024] fp32

    char* ws = (char*)d_ws;
    size_t off = 0;
    _Float16* pack1 = (_Float16*)(ws + off); off += (size_t)NN * DIM * 2;     // 2 MB
    _Float16* pack2 = (_Float16*)(ws + off); off += (size_t)DIM * NN * 2;     // 2 MB
    float*    wsq   = (float*)   (ws + off); off += (size_t)NN * 4;

    prep_pack_kernel<<<512, 256, 0, stream>>>(w, pack1, pack2);
    wsq_kernel<<<NN, 256, 0, stream>>>(w, wsq);
    fused_som_kernel<<<BATCH / 64, 1024, 0, stream>>>(x, pack1, pack2, wsq, out);
}

// Round 8
// 201.017 us; speedup vs baseline: 1.3447x; 1.2977x over previous
//
#include <hip/hip_runtime.h>

// Problem constants
static constexpr int BATCH = 16384;   // rows of x
static constexpr int DIM   = 1024;    // feature dim
static constexpr int NN    = 1024;    // 32*32 grid nodes

typedef _Float16 half8  __attribute__((ext_vector_type(8)));
typedef _Float16 half4v __attribute__((ext_vector_type(4)));
typedef float    f32x4  __attribute__((ext_vector_type(4)));

static constexpr float L2E = 1.44269504088896340736f;

// ---------------------------------------------------------------------------
// prep (merged): pack W into MFMA-fragment-major fp16 for both GEMMs
//                + wsqs[n] = L2E * ||w_n||^2.
// Fragment (16x16x32 f16 B-operand): lane l supplies
//   B[t_n*16 + (l&15)][t_k*32 + (l>>4)*8 + j], j=0..7  (one half8).
// P1[f=(t_n*32+t_k)][l][8] : B = w[n][d]    (GEMM1: S = x @ w^T)
// P2[f=(t_d*32+t_n)][l][8] : B = w[n][d]^T  (GEMM2: recon = c @ w)
// grid 512 x 256: block b packs fragments 4b..4b+3 (one per wave) and
// reduces wsq rows 2b, 2b+1 (2 waves per row, shfl + tiny LDS combine).
// ---------------------------------------------------------------------------
__global__ __launch_bounds__(256) void prep_kernel(const float* __restrict__ W,
                                                   _Float16* __restrict__ P1,
                                                   _Float16* __restrict__ P2,
                                                   float* __restrict__ wsq) {
    const int t = threadIdx.x;
    const int l = t & 63;
    const int v = t >> 6;
    const int f = blockIdx.x * 4 + v;          // 0..2047
    const int hi = f >> 5, lo = f & 31;
    {   // P1: n-tile = hi, k(d)-tile = lo
        int n  = hi * 16 + (l & 15);
        int k0 = lo * 32 + (l >> 4) * 8;
        const float* src = W + (size_t)n * DIM + k0;
        f32x4 a = *(const f32x4*)src;
        f32x4 b = *(const f32x4*)(src + 4);
        half8 h;
#pragma unroll
        for (int q = 0; q < 4; ++q) { h[q] = (_Float16)a[q]; h[4 + q] = (_Float16)b[q]; }
        *(half8*)(P1 + ((size_t)f * 64 + l) * 8) = h;
    }
    {   // P2: d-tile = hi, k(n)-tile = lo
        int d  = hi * 16 + (l & 15);
        int n0 = lo * 32 + (l >> 4) * 8;
        half8 h;
#pragma unroll
        for (int j = 0; j < 8; ++j) h[j] = (_Float16)W[(size_t)(n0 + j) * DIM + d];
        *(half8*)(P2 + ((size_t)f * 64 + l) * 8) = h;
    }
    {   // wsq: waves 0,1 -> row 2b; waves 2,3 -> row 2b+1
        const int row = blockIdx.x * 2 + (t >> 7);
        const int tt  = t & 127;               // 8 floats per thread
        const float* src = W + (size_t)row * DIM + tt * 8;
        f32x4 a = *(const f32x4*)src;
        f32x4 b = *(const f32x4*)(src + 4);
        float ss = a[0]*a[0] + a[1]*a[1] + a[2]*a[2] + a[3]*a[3]
                 + b[0]*b[0] + b[1]*b[1] + b[2]*b[2] + b[3]*b[3];
#pragma unroll
        for (int o = 32; o > 0; o >>= 1) ss += __shfl_xor(ss, o, 64);
        __shared__ float wred[4];
        if (l == 0) wred[v] = ss;
        __syncthreads();
        if (t == 0)   wsq[row]     = L2E * (wred[0] + wred[1]);
        if (t == 128) wsq[row]     = L2E * (wred[2] + wred[3]);
    }
}

// ---------------------------------------------------------------------------
// FUSED: per block = 64 rows of x.  16 waves x 1024 threads, 256 blocks.
// Wave w owns cols w*64 + ni*16 + (l&15), ni=0..3.
// SCHEDULE NOTE (rounds 5-7 lesson): with 1024-thread blocks the VGPR cap is
// a hard 128/wave (16 waves must co-reside).  Extending fragment live ranges
// across the K-step barrier (cross-barrier refill, 2-deep reg pipelines)
// overflows the allocator into per-iteration scratch spill/fill: +66MB FETCH,
// +172MB WRITE, +77us.  Keep ALL fragment loads in-step (round-4 schedule).
//   Phase A: raw dot acc = x@w^T in regs; x fp32 -> regs (nt), cvt fp16,
//            ds_write into xs dbuf; P1 fragments loaded at step top.
//   Phase B (NO-MAX softmax; logits v = 2*acc - wsq lie in ~[-21,18]):
//            e1 = exp2(2*L2E*acc - wsqs[col]); S2 wave-local (shfl), S1
//            cross-wave via one swizzled-LDS round; cu = e1^2*rcp(S1)*rcp(S2)
//            -> cs fp16 (row-unnormalized).
//   Phase C: recon = cu @ w, barrier-free K-loop, unroll-2, in-step loads.
//   Epilogue: row-normalize, stage through LDS, nontemporal f32x4 full-line
//            stores (plain scattered 4B => RMW; this measured 99MB WRITE).
// Element map: row = mi*16+(l>>4)*4+q; col n = w*64+ni*16+(l&15);
//   g1 = n>>5 = w*2+(ni>>1) [p];  g2 = n&31 = (ni&1)*16+(l&15) [j].
// LDS: xs 16K + BIG 128K (red/cs/stg union) + a1 8K + rowred 4K + rowinv.
// ---------------------------------------------------------------------------
__global__ __launch_bounds__(1024, 4) void fused_som_kernel(
    const float* __restrict__ X, const _Float16* __restrict__ P1,
    const _Float16* __restrict__ P2, const float* __restrict__ wsq,
    float* __restrict__ Out) {

    __shared__ __align__(16) _Float16 xs[2][64 * 64];   // 16 KB dbuf
    __shared__ __align__(16) char     BIG[131072];      // red / cs / stg union
    __shared__ __align__(16) float    a1_lds[64 * 32];  // 8 KB (stores 1/S1)
    __shared__ __align__(16) float    rowred[16 * 64];  // 4 KB
    __shared__ __align__(16) float    rowinv[64];

    const int t  = threadIdx.x;
    const int l  = t & 63;
    const int w  = t >> 6;
    const int r0 = blockIdx.x * 64;

    // swizzled index helpers (2-way max bank aliasing for cross-wave reduce)
    auto RIDX = [](int wv, int row, int g2) {
        return (wv * 64 + row) * 32 + (g2 ^ ((row & 4) << 2));
    };
    auto AIDX = [](int row, int g2) {
        return row * 32 + (g2 ^ ((row & 4) << 2));
    };

    // ---------------- Phase A ----------------
    const int srow = t >> 4;                  // staging row 0..63
    const int skq  = t & 15;                  // f32x4 index within 64-k tile

    auto xload = [&](int kt) -> f32x4 {
        return __builtin_nontemporal_load(
            (const f32x4*)(X + (size_t)(r0 + srow) * DIM + kt + skq * 4));
    };
    auto xwrite = [&](int buf, f32x4 v) {
        half4v h;
        h[0] = (_Float16)v[0]; h[1] = (_Float16)v[1];
        h[2] = (_Float16)v[2]; h[3] = (_Float16)v[3];
        int c = skq >> 1;                     // 16-B chunk 0..7
        *(half4v*)&xs[buf][srow * 64 + ((c ^ (srow & 7)) << 3) + ((skq & 1) << 2)] = h;
    };

    f32x4 acc[4][4] = {};
    {   // prologue: tile 0 -> xs[0]
        f32x4 xv = xload(0);
        xwrite(0, xv);
    }
    __syncthreads();

    for (int kt = 0; kt < DIM; kt += 64) {
        const int cur = (kt >> 6) & 1;
        const bool hasNext = (kt + 64 < DIM);
        f32x4 xv;
        if (hasNext) xv = xload(kt + 64);     // issue early: HBM under MFMAs

        const int tk0 = kt >> 5;
        half8 bf0[4], bf1[4];
#pragma unroll
        for (int ni = 0; ni < 4; ++ni) {
            const size_t fb = (size_t)(w * 4 + ni) * 32;
            bf0[ni] = *(const half8*)(P1 + ((fb + tk0) * 64 + l) * 8);
            bf1[ni] = *(const half8*)(P1 + ((fb + tk0 + 1) * 64 + l) * 8);
        }
        half8 af[4];
#pragma unroll
        for (int mi = 0; mi < 4; ++mi) {
            const _Float16* pa = &xs[cur][((l & 15) + mi * 16) * 64];
            af[mi] = *(const half8*)(pa + (((l >> 4)) ^ (l & 7)) * 8);
        }
        __builtin_amdgcn_s_setprio(1);
#pragma unroll
        for (int mi = 0; mi < 4; ++mi)
#pragma unroll
            for (int ni = 0; ni < 4; ++ni)
                acc[mi][ni] = __builtin_amdgcn_mfma_f32_16x16x32_f16(
                    af[mi], bf0[ni], acc[mi][ni], 0, 0, 0);
        __builtin_amdgcn_s_setprio(0);
#pragma unroll
        for (int mi = 0; mi < 4; ++mi) {
            const _Float16* pa = &xs[cur][((l & 15) + mi * 16) * 64];
            af[mi] = *(const half8*)(pa + ((4 + (l >> 4)) ^ (l & 7)) * 8);
        }
        __builtin_amdgcn_s_setprio(1);
#pragma unroll
        for (int mi = 0; mi < 4; ++mi)
#pragma unroll
            for (int ni = 0; ni < 4; ++ni)
                acc[mi][ni] = __builtin_amdgcn_mfma_f32_16x16x32_f16(
                    af[mi], bf1[ni], acc[mi][ni], 0, 0, 0);
        __builtin_amdgcn_s_setprio(0);
        __builtin_amdgcn_sched_barrier(0);    // pin cvt+ds_write after MFMAs
        if (hasNext) xwrite(cur ^ 1, xv);
        __syncthreads();
    }

    // ---------------- Phase B (no-max) ----------------
    // e1 = exp2(2*L2E*acc - wsqs[col])   (in place)
    float wq[4];
#pragma unroll
    for (int ni = 0; ni < 4; ++ni) wq[ni] = wsq[w * 64 + ni * 16 + (l & 15)];
#pragma unroll
    for (int mi = 0; mi < 4; ++mi)
#pragma unroll
        for (int ni = 0; ni < 4; ++ni)
#pragma unroll
            for (int q = 0; q < 4; ++q)
                acc[mi][ni][q] = exp2f(fmaf(acc[mi][ni][q], 2.0f * L2E, -wq[ni]));

    // S2 (sum over g2 = {j, l&15}; wave-local) -> reciprocal
    f32x4 rS2[4][2];
#pragma unroll
    for (int mi = 0; mi < 4; ++mi)
#pragma unroll
        for (int p = 0; p < 2; ++p) {
#pragma unroll
            for (int q = 0; q < 4; ++q) {
                float s = acc[mi][2 * p][q] + acc[mi][2 * p + 1][q];
                s += __shfl_xor(s, 1, 64);
                s += __shfl_xor(s, 2, 64);
                s += __shfl_xor(s, 4, 64);
                s += __shfl_xor(s, 8, 64);
                rS2[mi][p][q] = __builtin_amdgcn_rcpf(s);
            }
        }

    // S1 (sum over g1 = {w, p}): one cross-wave LDS round -> 1/S1 in a1_lds
    float* red = (float*)BIG;                 // [16][64][32] swizzled
#pragma unroll
    for (int mi = 0; mi < 4; ++mi)
#pragma unroll
        for (int j = 0; j < 2; ++j)
#pragma unroll
            for (int q = 0; q < 4; ++q) {
                int row = mi * 16 + (l >> 4) * 4 + q;
                red[RIDX(w, row, j * 16 + (l & 15))] =
                    acc[mi][j][q] + acc[mi][2 + j][q];
            }
    __syncthreads();
#pragma unroll
    for (int i = 0; i < 2; ++i) {
        int pr = t + i * 1024;
        int row = pr >> 5, g2 = pr & 31;
        float s = 0.f;
#pragma unroll
        for (int wv = 0; wv < 16; ++wv) s += red[RIDX(wv, row, g2)];
        a1_lds[AIDX(row, g2)] = __builtin_amdgcn_rcpf(s);
    }
    __syncthreads();                          // red dead; BIG becomes cs

    // cu = e1^2 * (1/S1) * (1/S2) -> cs fp16; per-row partial sums
    _Float16* cs = (_Float16*)BIG;            // [64][1024] chunk-swizzled
#pragma unroll
    for (int mi = 0; mi < 4; ++mi) {
        f32x4 rs = {0.f, 0.f, 0.f, 0.f};
#pragma unroll
        for (int j = 0; j < 2; ++j) {
            f32x4 a1v;
#pragma unroll
            for (int q = 0; q < 4; ++q) {
                int row = mi * 16 + (l >> 4) * 4 + q;
                a1v[q] = a1_lds[AIDX(row, j * 16 + (l & 15))];
            }
#pragma unroll
            for (int p = 0; p < 2; ++p) {
                int ni  = 2 * p + j;
                int col = w * 64 + ni * 16 + (l & 15);
                int chunk = col >> 3;
#pragma unroll
                for (int q = 0; q < 4; ++q) {
                    float e = acc[mi][ni][q];
                    float cu = ((e * e) * a1v[q]) * rS2[mi][p][q];
                    rs[q] += cu;
                    int row = mi * 16 + (l >> 4) * 4 + q;
                    cs[row * 1024 + ((chunk ^ (row & 7)) << 3) + (col & 7)] =
                        (_Float16)cu;
                }
            }
        }
#pragma unroll
        for (int q = 0; q < 4; ++q) {
            float sv = rs[q];
            sv += __shfl_xor(sv, 1, 64);
            sv += __shfl_xor(sv, 2, 64);
            sv += __shfl_xor(sv, 4, 64);
            sv += __shfl_xor(sv, 8, 64);
            if ((l & 15) == 0) rowred[w * 64 + mi * 16 + (l >> 4) * 4 + q] = sv;
        }
    }
    __syncthreads();                          // cs + rowred ready

    if (t < 64) {
        float tot = 0.f;
#pragma unroll
        for (int wv = 0; wv < 16; ++wv) tot += rowred[wv * 64 + t];
        rowinv[t] = 1.f / (tot + 1e-8f);
    }

    // ---------------- Phase C: recon = cu @ w (barrier-free K-loop) --------
    f32x4 acc2[4][4] = {};
#pragma unroll 2
    for (int kt = 0; kt < NN; kt += 32) {
        const int tn = kt >> 5;
        half8 bf[4], af2[4];
#pragma unroll
        for (int ni = 0; ni < 4; ++ni)
            bf[ni] = *(const half8*)(P2 +
                (((size_t)(w * 4 + ni) * 32 + tn) * 64 + l) * 8);
#pragma unroll
        for (int mi = 0; mi < 4; ++mi) {
            int row = (l & 15) + mi * 16;
            int kc  = tn * 4 + (l >> 4);
            af2[mi] = *(const half8*)(cs + row * 1024 + ((kc ^ (row & 7)) << 3));
        }
        __builtin_amdgcn_s_setprio(1);
#pragma unroll
        for (int mi = 0; mi < 4; ++mi)
#pragma unroll
            for (int ni = 0; ni < 4; ++ni)
                acc2[mi][ni] = __builtin_amdgcn_mfma_f32_16x16x32_f16(
                    af2[mi], bf[ni], acc2[mi][ni], 0, 0, 0);
        __builtin_amdgcn_s_setprio(0);
    }

    // ---------------- epilogue: LDS-staged full-line nt stores -------------
    __syncthreads();                          // cs reads done; rowinv visible
    float* stg = (float*)BIG;                 // [32][1024] f32, col-swizzled
#pragma unroll
    for (int half = 0; half < 2; ++half) {
        if (half) __syncthreads();            // previous read round done
#pragma unroll
        for (int mm = 0; mm < 2; ++mm) {
            const int mi = half * 2 + mm;
#pragma unroll
            for (int ni = 0; ni < 4; ++ni) {
                const int col = w * 64 + ni * 16 + (l & 15);
#pragma unroll
                for (int q = 0; q < 4; ++q) {
                    const int rr = (l >> 4) * 4 + q;          // 0..15
                    const float inv = rowinv[mi * 16 + rr];
                    stg[(mm * 16 + rr) * 1024 + (col ^ ((rr & 4) << 2))] =
                        acc2[mi][ni][q] * inv;
                }
            }
        }
        __syncthreads();
#pragma unroll
        for (int i = 0; i < 8; ++i) {
            const int c  = t + i * 1024;      // 8192 f32x4 chunks
            const int rr = c >> 8;            // 0..31
            const int c4 = c & 255;
            f32x4 v = *(const f32x4*)&stg[rr * 1024 + ((c4 * 4) ^ ((rr & 4) << 2))];
            __builtin_nontemporal_store(v,
                (f32x4*)(Out + (size_t)(r0 + half * 32 + rr) * DIM + c4 * 4));
        }
    }
}

// ---------------------------------------------------------------------------
extern "C" void kernel_launch(void* const* d_in, const int* in_sizes, int n_in,
                              void* d_out, int out_size, void* d_ws, size_t ws_size,
                              hipStream_t stream) {
    const float* x = (const float*)d_in[0];        // [16384, 1024] fp32
    const float* w = (const float*)d_in[1];        // [32, 32, 1024] fp32
    float* out = (float*)d_out;                    // [16384, 1024] fp32

    char* ws = (char*)d_ws;
    size_t off = 0;
    _Float16* pack1 = (_Float16*)(ws + off); off += (size_t)NN * DIM * 2;     // 2 MB
    _Float16* pack2 = (_Float16*)(ws + off); off += (size_t)DIM * NN * 2;     // 2 MB
    float*    wsq   = (float*)   (ws + off); off += (size_t)NN * 4;

    prep_kernel<<<512, 256, 0, stream>>>(w, pack1, pack2, wsq);
    fused_som_kernel<<<BATCH / 64, 1024, 0, stream>>>(x, pack1, pack2, wsq, out);
}